// Round 12
// baseline (925.317 us; speedup 1.0000x reference)
//
#include <hip/hip_runtime.h>
#include <hip/hip_bf16.h>

// ---------------------------------------------------------------------------
// GCNRegression: 4x (GEMM 128x128 + symmetric-norm aggregation + ReLU),
// then global mean pool (128 graphs) + FC(128->1).
//
// R11 notes: 128B granule validated (4.46 cyc/sector, best). This round:
// src-half split CSR (csr_lo: src<half, csr_hi: src>=half) + two agg
// launches per layer -> per-launch gather working set 3.2MB/slice fits the
// 4MB XCD L2 (R8 showed 97% hit at 3.2MB). Pass1 stores raw lo-sums; pass2
// adds hi-sums + self + epilogue.
// ---------------------------------------------------------------------------

// ---- degree histograms (lo/hi src halves), int4 reads ---------------------
__global__ void count_deg_kernel(const int* __restrict__ src, const int* __restrict__ dst,
                                 int* __restrict__ deg_lo, int* __restrict__ deg_hi,
                                 int E, int half) {
    int i = blockIdx.x * blockDim.x + threadIdx.x;
    int e = i * 4;
    if (e + 3 < E) {
        int4 s = *(const int4*)(src + e);
        int4 d = *(const int4*)(dst + e);
        atomicAdd((s.x < half ? deg_lo : deg_hi) + d.x, 1);
        atomicAdd((s.y < half ? deg_lo : deg_hi) + d.y, 1);
        atomicAdd((s.z < half ? deg_lo : deg_hi) + d.z, 1);
        atomicAdd((s.w < half ? deg_lo : deg_hi) + d.w, 1);
    } else {
        for (; e < E; e++)
            atomicAdd((src[e] < half ? deg_lo : deg_hi) + dst[e], 1);
    }
}

// ---- dinv = 1/sqrt(deg+1); zero the pad rows of h0/h1 (4 slices x 32ch) ---
__global__ void dinv_kernel(const int* __restrict__ deg_lo, const int* __restrict__ deg_hi,
                            float* __restrict__ dinv,
                            float* __restrict__ h0, float* __restrict__ h1,
                            int n, int ns) {
    int i = blockIdx.x * blockDim.x + threadIdx.x;
    if (i < n) dinv[i] = (float)(1.0 / sqrt((double)(deg_lo[i] + deg_hi[i] + 1)));
    if (i < 128) {                       // 4 slices x 32 channels pad row
        int p = i >> 5, c = i & 31;
        size_t off = (size_t)p * ns * 32 + (size_t)n * 32 + c;
        h0[off] = 0.f;
        h1[off] = 0.f;
    }
}

// ---- single-block exclusive scan -> row_ptr -------------------------------
__global__ void scan_kernel(const int* __restrict__ cnt, int* __restrict__ row_ptr, int n) {
    __shared__ int sums[1024];
    int t = threadIdx.x;
    int per = (n + 1023) >> 10;
    int s = t * per;
    int e = s + per; if (e > n) e = n; if (s > n) s = n;
    int acc = 0;
    for (int i = s; i < e; i++) acc += cnt[i];
    sums[t] = acc;
    __syncthreads();
    for (int off = 1; off < 1024; off <<= 1) {
        int u = (t >= off) ? sums[t - off] : 0;
        __syncthreads();
        sums[t] += u;
        __syncthreads();
    }
    int excl = sums[t] - acc;
    int run = excl;
    for (int i = s; i < e; i++) { row_ptr[i] = run; run += cnt[i]; }
    if (t == 1023) row_ptr[n] = sums[1023];
}

// ---- CSR fill into lo/hi structures, XCD-range-partitioned ----------------
__global__ __launch_bounds__(256) void csr_fill_kernel(const int* __restrict__ src,
                                                       const int* __restrict__ dst,
                                                       const int* __restrict__ row_lo,
                                                       const int* __restrict__ row_hi,
                                                       int* __restrict__ fill_lo,
                                                       int* __restrict__ fill_hi,
                                                       unsigned short* __restrict__ csr_lo,
                                                       unsigned short* __restrict__ csr_hi,
                                                       int E, int N, int half) {
    int g  = blockIdx.x & 7;
    int gb = blockIdx.x >> 3;
    int group_blocks = gridDim.x >> 3;
    int R  = (N + 7) >> 3;
    int lo = g * R;
    int hi = lo + R; if (hi > N) hi = N;

    int tig    = gb * blockDim.x + threadIdx.x;
    int stride = group_blocks * blockDim.x;
    int nq = (E + 3) >> 2;

    for (int q = tig; q < nq; q += stride) {
        int e = q * 4;
        if (e + 3 < E) {
            int4 d = *(const int4*)(dst + e);
            int4 s = *(const int4*)(src + e);
            if (d.x >= lo && d.x < hi) {
                if (s.x < half) { int pos = row_lo[d.x] + atomicAdd(&fill_lo[d.x], 1); csr_lo[pos] = (unsigned short)s.x; }
                else            { int pos = row_hi[d.x] + atomicAdd(&fill_hi[d.x], 1); csr_hi[pos] = (unsigned short)s.x; }
            }
            if (d.y >= lo && d.y < hi) {
                if (s.y < half) { int pos = row_lo[d.y] + atomicAdd(&fill_lo[d.y], 1); csr_lo[pos] = (unsigned short)s.y; }
                else            { int pos = row_hi[d.y] + atomicAdd(&fill_hi[d.y], 1); csr_hi[pos] = (unsigned short)s.y; }
            }
            if (d.z >= lo && d.z < hi) {
                if (s.z < half) { int pos = row_lo[d.z] + atomicAdd(&fill_lo[d.z], 1); csr_lo[pos] = (unsigned short)s.z; }
                else            { int pos = row_hi[d.z] + atomicAdd(&fill_hi[d.z], 1); csr_hi[pos] = (unsigned short)s.z; }
            }
            if (d.w >= lo && d.w < hi) {
                if (s.w < half) { int pos = row_lo[d.w] + atomicAdd(&fill_lo[d.w], 1); csr_lo[pos] = (unsigned short)s.w; }
                else            { int pos = row_hi[d.w] + atomicAdd(&fill_hi[d.w], 1); csr_hi[pos] = (unsigned short)s.w; }
            }
        } else {
            for (; e < E; e++) {
                int d = dst[e];
                if (d >= lo && d < hi) {
                    int s = src[e];
                    if (s < half) { int pos = row_lo[d] + atomicAdd(&fill_lo[d], 1); csr_lo[pos] = (unsigned short)s; }
                    else          { int pos = row_hi[d] + atomicAdd(&fill_hi[d], 1); csr_hi[pos] = (unsigned short)s; }
                }
            }
        }
    }
}

// ---- GEMM: C = (A @ W) * dinv[row], C channel-blocked [4][ns][32] ---------
__global__ __launch_bounds__(256) void gemm_kernel(const float* __restrict__ A,
                                                   const float* __restrict__ W,
                                                   const float* __restrict__ dinv,
                                                   float* __restrict__ C, int n, int ns,
                                                   int a_blocked) {
    __shared__ float sW[128 * 32];
    int t = threadIdx.x;
    int col0 = (blockIdx.x & 3) * 32;
    int row0 = (blockIdx.x >> 2) * 64;

    #pragma unroll
    for (int i = 0; i < 4; i++) {
        int fidx = t + 256 * i;            // 1024 float4
        int k  = fidx >> 3;
        int c4 = fidx & 7;
        *(float4*)(sW + k * 32 + c4 * 4) =
            *(const float4*)(W + (size_t)k * 128 + col0 + c4 * 4);
    }
    __syncthreads();

    int cg = (t & 7) * 4;
    int rg = (t >> 3) * 2;
    int rbase = row0 + rg;

    int rr_[2];
    #pragma unroll
    for (int r = 0; r < 2; r++) {
        int rr = rbase + r; if (rr > n - 1) rr = n - 1;
        rr_[r] = rr;
    }
    auto aptr = [&](int r, int kb) -> const float* {
        return a_blocked
            ? (A + ((size_t)(kb >> 1) * ns + rr_[r]) * 32 + ((kb & 1) * 16))
            : (A + (size_t)rr_[r] * 128 + kb * 16);
    };

    float acc[2][4];
    #pragma unroll
    for (int r = 0; r < 2; r++)
        #pragma unroll
        for (int c = 0; c < 4; c++) acc[r][c] = 0.f;

    float4 bufA[2][2], bufB[2][2];
    #pragma unroll
    for (int r = 0; r < 2; r++) {
        const float* ap = aptr(r, 0);
        bufA[r][0] = *(const float4*)(ap + 0);
        bufA[r][1] = *(const float4*)(ap + 4);
        bufB[r][0] = *(const float4*)(ap + 8);
        bufB[r][1] = *(const float4*)(ap + 12);
    }

    #pragma unroll 1
    for (int kb = 0; kb < 8; kb++) {
        const float* wrow = sW + kb * 16 * 32 + cg;
        #pragma unroll
        for (int kk = 0; kk < 8; kk++) {
            float4 w = *(const float4*)(wrow + kk * 32);
            #pragma unroll
            for (int r = 0; r < 2; r++) {
                float4 aq = bufA[r][kk >> 2];
                float av = ((kk & 3) == 0) ? aq.x : ((kk & 3) == 1) ? aq.y
                         : ((kk & 3) == 2) ? aq.z : aq.w;
                acc[r][0] = fmaf(av, w.x, acc[r][0]);
                acc[r][1] = fmaf(av, w.y, acc[r][1]);
                acc[r][2] = fmaf(av, w.z, acc[r][2]);
                acc[r][3] = fmaf(av, w.w, acc[r][3]);
            }
        }
        if (kb < 7) {
            #pragma unroll
            for (int r = 0; r < 2; r++) {
                const float* ap = aptr(r, kb + 1);
                bufA[r][0] = *(const float4*)(ap + 0);
                bufA[r][1] = *(const float4*)(ap + 4);
            }
        }
        #pragma unroll
        for (int kk = 0; kk < 8; kk++) {
            float4 w = *(const float4*)(wrow + (8 + kk) * 32);
            #pragma unroll
            for (int r = 0; r < 2; r++) {
                float4 aq = bufB[r][kk >> 2];
                float av = ((kk & 3) == 0) ? aq.x : ((kk & 3) == 1) ? aq.y
                         : ((kk & 3) == 2) ? aq.z : aq.w;
                acc[r][0] = fmaf(av, w.x, acc[r][0]);
                acc[r][1] = fmaf(av, w.y, acc[r][1]);
                acc[r][2] = fmaf(av, w.z, acc[r][2]);
                acc[r][3] = fmaf(av, w.w, acc[r][3]);
            }
        }
        if (kb < 7) {
            #pragma unroll
            for (int r = 0; r < 2; r++) {
                const float* ap = aptr(r, kb + 1);
                bufB[r][0] = *(const float4*)(ap + 8);
                bufB[r][1] = *(const float4*)(ap + 12);
            }
        }
    }

    int cb = col0 + cg;
    float* Cb = C + (size_t)(cb >> 5) * ns * 32 + (cb & 31);
    #pragma unroll
    for (int r = 0; r < 2; r++) {
        int rr = rbase + r;
        if (rr < n) {
            float dsc = dinv[rr];
            *(float4*)(Cb + (size_t)rr * 32) =
                make_float4(acc[r][0] * dsc, acc[r][1] * dsc,
                            acc[r][2] * dsc, acc[r][3] * dsc);
        }
    }
}

// ---- Agg pass 1: lo-half gathers only; store raw partial sums -------------
__global__ __launch_bounds__(256) void agg_pass1_kernel(const float* __restrict__ h,
                                                        const int* __restrict__ row_ptr,
                                                        const unsigned short* __restrict__ csr,
                                                        float* __restrict__ out,
                                                        int n, int ns) {
    int p = blockIdx.x & 3;
    int i = (blockIdx.x >> 2) * 32 + (threadIdx.x >> 3);
    int q = threadIdx.x & 7;
    bool valid = (i < n);
    int iv = valid ? i : 0;

    const float* slice  = h   + (size_t)p * ns * 32;
    float*       oslice = out + (size_t)p * ns * 32;

    int beg = row_ptr[iv];
    int end = valid ? row_ptr[iv + 1] : beg;
    int qoff = q << 2;

    float4 acc = make_float4(0.f, 0.f, 0.f, 0.f);

    int e = beg;
    int s0 = (int)__builtin_nontemporal_load(csr + e);
    int s1 = (int)__builtin_nontemporal_load(csr + e + 1);
    int s2 = (int)__builtin_nontemporal_load(csr + e + 2);
    int s3 = (int)__builtin_nontemporal_load(csr + e + 3);

    while (__any(e < end)) {
        int en = e + 4;
        int t0 = (int)__builtin_nontemporal_load(csr + en);
        int t1 = (int)__builtin_nontemporal_load(csr + en + 1);
        int t2 = (int)__builtin_nontemporal_load(csr + en + 2);
        int t3 = (int)__builtin_nontemporal_load(csr + en + 3);

        int g0 = (e     < end) ? s0 : n;
        int g1 = (e + 1 < end) ? s1 : n;
        int g2 = (e + 2 < end) ? s2 : n;
        int g3 = (e + 3 < end) ? s3 : n;

        float4 v0 = *(const float4*)(slice + ((size_t)g0 << 5) + qoff);
        float4 v1 = *(const float4*)(slice + ((size_t)g1 << 5) + qoff);
        float4 v2 = *(const float4*)(slice + ((size_t)g2 << 5) + qoff);
        float4 v3 = *(const float4*)(slice + ((size_t)g3 << 5) + qoff);

        acc.x += v0.x; acc.y += v0.y; acc.z += v0.z; acc.w += v0.w;
        acc.x += v1.x; acc.y += v1.y; acc.z += v1.z; acc.w += v1.w;
        acc.x += v2.x; acc.y += v2.y; acc.z += v2.z; acc.w += v2.w;
        acc.x += v3.x; acc.y += v3.y; acc.z += v3.z; acc.w += v3.w;

        e = en; s0 = t0; s1 = t1; s2 = t2; s3 = t3;
    }

    if (valid)
        *(float4*)(oslice + ((size_t)i << 5) + qoff) = acc;
}

// ---- Agg pass 2: hi-half gathers + partial + self + epilogue --------------
// out[i] = relu( (hi_sum + partial + slice[i]) * dinv[i] + b )
__global__ __launch_bounds__(256) void agg_pass2_kernel(const float* __restrict__ h,
                                                        const int* __restrict__ row_ptr,
                                                        const unsigned short* __restrict__ csr,
                                                        const float* __restrict__ dinv,
                                                        const float* __restrict__ bias,
                                                        float* __restrict__ out,
                                                        int n, int ns) {
    int p = blockIdx.x & 3;
    int i = (blockIdx.x >> 2) * 32 + (threadIdx.x >> 3);
    int q = threadIdx.x & 7;
    bool valid = (i < n);
    int iv = valid ? i : 0;

    const float* slice  = h   + (size_t)p * ns * 32;
    float*       oslice = out + (size_t)p * ns * 32;

    int beg = row_ptr[iv];
    int end = valid ? row_ptr[iv + 1] : beg;
    int qoff = q << 2;

    float4 acc = make_float4(0.f, 0.f, 0.f, 0.f);

    int e = beg;
    int s0 = (int)__builtin_nontemporal_load(csr + e);
    int s1 = (int)__builtin_nontemporal_load(csr + e + 1);
    int s2 = (int)__builtin_nontemporal_load(csr + e + 2);
    int s3 = (int)__builtin_nontemporal_load(csr + e + 3);

    while (__any(e < end)) {
        int en = e + 4;
        int t0 = (int)__builtin_nontemporal_load(csr + en);
        int t1 = (int)__builtin_nontemporal_load(csr + en + 1);
        int t2 = (int)__builtin_nontemporal_load(csr + en + 2);
        int t3 = (int)__builtin_nontemporal_load(csr + en + 3);

        int g0 = (e     < end) ? s0 : n;
        int g1 = (e + 1 < end) ? s1 : n;
        int g2 = (e + 2 < end) ? s2 : n;
        int g3 = (e + 3 < end) ? s3 : n;

        float4 v0 = *(const float4*)(slice + ((size_t)g0 << 5) + qoff);
        float4 v1 = *(const float4*)(slice + ((size_t)g1 << 5) + qoff);
        float4 v2 = *(const float4*)(slice + ((size_t)g2 << 5) + qoff);
        float4 v3 = *(const float4*)(slice + ((size_t)g3 << 5) + qoff);

        acc.x += v0.x; acc.y += v0.y; acc.z += v0.z; acc.w += v0.w;
        acc.x += v1.x; acc.y += v1.y; acc.z += v1.z; acc.w += v1.w;
        acc.x += v2.x; acc.y += v2.y; acc.z += v2.z; acc.w += v2.w;
        acc.x += v3.x; acc.y += v3.y; acc.z += v3.z; acc.w += v3.w;

        e = en; s0 = t0; s1 = t1; s2 = t2; s3 = t3;
    }

    if (valid) {
        float di = dinv[i];
        float4 part = *(float4*)(oslice + ((size_t)i << 5) + qoff);
        float4 self = *(const float4*)(slice + ((size_t)i << 5) + qoff);
        float4 b4   = *(const float4*)(bias + p * 32 + qoff);
        float4 o;
        o.x = fmaxf(fmaf(acc.x + part.x + self.x, di, b4.x), 0.f);
        o.y = fmaxf(fmaf(acc.y + part.y + self.y, di, b4.y), 0.f);
        o.z = fmaxf(fmaf(acc.z + part.z + self.z, di, b4.z), 0.f);
        o.w = fmaxf(fmaf(acc.w + part.w + self.w, di, b4.w), 0.f);
        *(float4*)(oslice + ((size_t)i << 5) + qoff) = o;
    }
}

// ---- pool stage 1: deterministic fp64 partials, one slot per (g,s) --------
__global__ __launch_bounds__(128) void pool_partial_kernel(const float* __restrict__ h,
                                                           const int* __restrict__ batch,
                                                           double* __restrict__ partials,
                                                           int n, int ns, int S) {
    int g = blockIdx.x / S;
    int s = blockIdx.x % S;
    int c = threadIdx.x;
    const float* hb = h + (size_t)(c >> 5) * ns * 32 + (c & 31);

    int lo = 0, hi = n;
    while (lo < hi) { int mid = (lo + hi) >> 1; if (batch[mid] < g) lo = mid + 1; else hi = mid; }
    int start = lo;
    lo = start; hi = n;
    while (lo < hi) { int mid = (lo + hi) >> 1; if (batch[mid] < g + 1) lo = mid + 1; else hi = mid; }
    int end = lo;

    int cnt = end - start;
    int per = (cnt + S - 1) / S;
    int rs = start + s * per;
    int re = rs + per; if (re > end) re = end;

    double a0 = 0.0, a1 = 0.0, a2 = 0.0, a3 = 0.0;
    int r = rs;
    for (; r + 4 <= re; r += 4) {
        a0 += (double)hb[(size_t)(r + 0) * 32];
        a1 += (double)hb[(size_t)(r + 1) * 32];
        a2 += (double)hb[(size_t)(r + 2) * 32];
        a3 += (double)hb[(size_t)(r + 3) * 32];
    }
    for (; r < re; r++) a0 += (double)hb[(size_t)r * 32];
    partials[(size_t)(g * S + s) * 128 + c] = (a0 + a1) + (a2 + a3);
}

// ---- pool stage 2: reduce S partials, mean + FC(128->1), fp64 -------------
__global__ __launch_bounds__(128) void pool_fc_final_kernel(const double* __restrict__ partials,
                                                            const int* __restrict__ batch,
                                                            const float* __restrict__ Wfc,
                                                            const float* __restrict__ bfc,
                                                            float* __restrict__ out,
                                                            int n, int S) {
    int g = blockIdx.x;
    int c = threadIdx.x;

    int lo = 0, hi = n;
    while (lo < hi) { int mid = (lo + hi) >> 1; if (batch[mid] < g) lo = mid + 1; else hi = mid; }
    int start = lo;
    lo = start; hi = n;
    while (lo < hi) { int mid = (lo + hi) >> 1; if (batch[mid] < g + 1) lo = mid + 1; else hi = mid; }
    int cnt = lo - start;

    double sum = 0.0;
    for (int s = 0; s < S; s++) sum += partials[(size_t)(g * S + s) * 128 + c];
    double mean = sum / (double)(cnt > 0 ? cnt : 1);
    double v = mean * (double)Wfc[c];

    __shared__ double red[128];
    red[c] = v;
    __syncthreads();
    for (int off = 64; off > 0; off >>= 1) {
        if (c < off) red[c] += red[c + off];
        __syncthreads();
    }
    if (c == 0) out[g] = (float)(red[0] + (double)bfc[0]);
}

// ---------------------------------------------------------------------------
extern "C" void kernel_launch(void* const* d_in, const int* in_sizes, int n_in,
                              void* d_out, int out_size, void* d_ws, size_t ws_size,
                              hipStream_t stream) {
    const float* x          = (const float*)d_in[0];
    const int*   edge_index = (const int*)d_in[1];
    const int*   batch      = (const int*)d_in[2];
    const float* W1  = (const float*)d_in[3];
    const float* b1  = (const float*)d_in[4];
    const float* W2  = (const float*)d_in[5];
    const float* b2  = (const float*)d_in[6];
    const float* Wfc = (const float*)d_in[7];
    const float* bfc = (const float*)d_in[8];
    float* out = (float*)d_out;

    const int N = in_sizes[2];       // 50000
    const int E = in_sizes[1] / 2;   // 1600000
    const int G = out_size;          // 128 graphs
    const int NS = N + 1;            // slice stride in rows (pad row = zeros)
    const int HALF = N >> 1;

    const int* e_src = edge_index;
    const int* e_dst = edge_index + E;

    char* p = (char*)d_ws;
    auto alloc = [&](size_t bytes) {
        void* r = (void*)p;
        p += (bytes + 255) & ~(size_t)255;
        return r;
    };
    const int S = 8;
    float*          h0        = (float*)alloc((size_t)NS * 128 * 4);
    float*          h1        = (float*)alloc((size_t)NS * 128 * 4);
    unsigned short* csr_lo    = (unsigned short*)alloc(((size_t)E + 1024) * 2);
    unsigned short* csr_hi    = (unsigned short*)alloc(((size_t)E + 1024) * 2);
    int*            row_lo    = (int*)  alloc((size_t)(N + 1) * 4);
    int*            row_hi    = (int*)  alloc((size_t)(N + 1) * 4);
    int*            deg_lo    = (int*)  alloc((size_t)N * 4);
    int*            deg_hi    = (int*)  alloc((size_t)N * 4);
    int*            fill_lo   = (int*)  alloc((size_t)N * 4);
    int*            fill_hi   = (int*)  alloc((size_t)N * 4);
    float*          dinv      = (float*)alloc((size_t)N * 4);
    double*         partials  = (double*)alloc((size_t)G * S * 128 * 8);
    (void)ws_size; (void)n_in;

    hipMemsetAsync(deg_lo,  0, (size_t)N * 4, stream);
    hipMemsetAsync(deg_hi,  0, (size_t)N * 4, stream);
    hipMemsetAsync(fill_lo, 0, (size_t)N * 4, stream);
    hipMemsetAsync(fill_hi, 0, (size_t)N * 4, stream);

    int tb = 256;
    int e4 = (E + 3) / 4;
    count_deg_kernel<<<(e4 + tb - 1) / tb, tb, 0, stream>>>(e_src, e_dst, deg_lo, deg_hi, E, HALF);
    dinv_kernel<<<(N + tb - 1) / tb, tb, 0, stream>>>(deg_lo, deg_hi, dinv, h0, h1, N, NS);
    scan_kernel<<<1, 1024, 0, stream>>>(deg_lo, row_lo, N);
    scan_kernel<<<1, 1024, 0, stream>>>(deg_hi, row_hi, N);
    csr_fill_kernel<<<1024, tb, 0, stream>>>(e_src, e_dst, row_lo, row_hi,
                                             fill_lo, fill_hi, csr_lo, csr_hi, E, N, HALF);

    int gemm_blocks = 4 * ((N + 63) / 64);
    int agg_blocks  = 4 * ((N + 31) / 32);

    gemm_kernel<<<gemm_blocks, 256, 0, stream>>>(x, W1, dinv, h1, N, NS, 0);
    agg_pass1_kernel<<<agg_blocks, 256, 0, stream>>>(h1, row_lo, csr_lo, h0, N, NS);
    agg_pass2_kernel<<<agg_blocks, 256, 0, stream>>>(h1, row_hi, csr_hi, dinv, b1, h0, N, NS);

    for (int l = 0; l < 3; l++) {
        gemm_kernel<<<gemm_blocks, 256, 0, stream>>>(h0, W2, dinv, h1, N, NS, 1);
        agg_pass1_kernel<<<agg_blocks, 256, 0, stream>>>(h1, row_lo, csr_lo, h0, N, NS);
        agg_pass2_kernel<<<agg_blocks, 256, 0, stream>>>(h1, row_hi, csr_hi, dinv, b2, h0, N, NS);
    }

    pool_partial_kernel<<<G * S, 128, 0, stream>>>(h0, batch, partials, N, NS, S);
    pool_fc_final_kernel<<<G, 128, 0, stream>>>(partials, batch, Wfc, bfc, out, N, S);
}

// Round 13
// 776.923 us; speedup vs baseline: 1.1910x; 1.1910x over previous
//
#include <hip/hip_runtime.h>
#include <hip/hip_bf16.h>

// ---------------------------------------------------------------------------
// GCNRegression: 4x (GEMM 128x128 + symmetric-norm aggregation + ReLU),
// then global mean pool (128 graphs) + FC(128->1).
//
// R12 notes: single-block scan_kernel was 78us/dispatch (0.15% occupancy,
// latency chain) and ran TWICE. -> multi-block 3-phase scan over merged
// deg[2N] (lo|hi) giving both row ranges in one pass; single csr buffer:
// node i lo = [row[i],row[i+1]), hi = [row[N+i],row[N+i+1]), row[2N]=E.
// ---------------------------------------------------------------------------

// ---- degree histogram into deg[2N] (lo: [0,N), hi: [N,2N)) ----------------
__global__ void count_deg_kernel(const int* __restrict__ src, const int* __restrict__ dst,
                                 int* __restrict__ deg, int E, int half, int N) {
    int i = blockIdx.x * blockDim.x + threadIdx.x;
    int e = i * 4;
    if (e + 3 < E) {
        int4 s = *(const int4*)(src + e);
        int4 d = *(const int4*)(dst + e);
        atomicAdd(&deg[d.x + (s.x < half ? 0 : N)], 1);
        atomicAdd(&deg[d.y + (s.y < half ? 0 : N)], 1);
        atomicAdd(&deg[d.z + (s.z < half ? 0 : N)], 1);
        atomicAdd(&deg[d.w + (s.w < half ? 0 : N)], 1);
    } else {
        for (; e < E; e++)
            atomicAdd(&deg[dst[e] + (src[e] < half ? 0 : N)], 1);
    }
}

// ---- dinv = 1/sqrt(deg+1); zero the pad rows of h0/h1 (4 slices x 32ch) ---
__global__ void dinv_kernel(const int* __restrict__ deg, float* __restrict__ dinv,
                            float* __restrict__ h0, float* __restrict__ h1,
                            int n, int ns) {
    int i = blockIdx.x * blockDim.x + threadIdx.x;
    if (i < n) dinv[i] = (float)(1.0 / sqrt((double)(deg[i] + deg[n + i] + 1)));
    if (i < 128) {                       // 4 slices x 32 channels pad row
        int p = i >> 5, c = i & 31;
        size_t off = (size_t)p * ns * 32 + (size_t)n * 32 + c;
        h0[off] = 0.f;
        h1[off] = 0.f;
    }
}

// ---- multi-block exclusive scan (3 phases) --------------------------------
__global__ void scan_blocksum_kernel(const int* __restrict__ cnt, int* __restrict__ bsum,
                                     int n2) {
    __shared__ int red[256];
    int t = threadIdx.x;
    int i = blockIdx.x * 256 + t;
    red[t] = (i < n2) ? cnt[i] : 0;
    __syncthreads();
    for (int off = 128; off > 0; off >>= 1) {
        if (t < off) red[t] += red[t + off];
        __syncthreads();
    }
    if (t == 0) bsum[blockIdx.x] = red[0];
}

__global__ __launch_bounds__(1024) void scan_bsum_kernel(const int* __restrict__ bsum,
                                                         int* __restrict__ boff, int nb) {
    __shared__ int s[1024];
    int t = threadIdx.x;
    int v = (t < nb) ? bsum[t] : 0;
    s[t] = v;
    __syncthreads();
    for (int off = 1; off < 1024; off <<= 1) {
        int u = (t >= off) ? s[t - off] : 0;
        __syncthreads();
        s[t] += u;
        __syncthreads();
    }
    if (t < nb) boff[t] = s[t] - v;
}

__global__ void scan_final_kernel(const int* __restrict__ cnt, const int* __restrict__ boff,
                                  int* __restrict__ row, int n2) {
    __shared__ int s[256];
    int t = threadIdx.x;
    int b = blockIdx.x;
    int i = b * 256 + t;
    int v = (i < n2) ? cnt[i] : 0;
    s[t] = v;
    __syncthreads();
    for (int off = 1; off < 256; off <<= 1) {
        int u = (t >= off) ? s[t - off] : 0;
        __syncthreads();
        s[t] += u;
        __syncthreads();
    }
    int incl = s[t];
    int base = boff[b];
    if (i < n2) row[i] = base + incl - v;
    if (i == n2 - 1) row[n2] = base + incl;
}

// ---- CSR fill into single buffer (lo|hi ranges), XCD-partitioned ----------
__global__ __launch_bounds__(256) void csr_fill_kernel(const int* __restrict__ src,
                                                       const int* __restrict__ dst,
                                                       const int* __restrict__ row,
                                                       int* __restrict__ fill,
                                                       unsigned short* __restrict__ csr,
                                                       int E, int N, int half) {
    int g  = blockIdx.x & 7;
    int gb = blockIdx.x >> 3;
    int group_blocks = gridDim.x >> 3;
    int R  = (N + 7) >> 3;
    int lo = g * R;
    int hi = lo + R; if (hi > N) hi = N;

    int tig    = gb * blockDim.x + threadIdx.x;
    int stride = group_blocks * blockDim.x;
    int nq = (E + 3) >> 2;

    for (int q = tig; q < nq; q += stride) {
        int e = q * 4;
        if (e + 3 < E) {
            int4 d = *(const int4*)(dst + e);
            int4 s = *(const int4*)(src + e);
            if (d.x >= lo && d.x < hi) {
                int slot = d.x + (s.x < half ? 0 : N);
                int pos = row[slot] + atomicAdd(&fill[slot], 1);
                csr[pos] = (unsigned short)s.x;
            }
            if (d.y >= lo && d.y < hi) {
                int slot = d.y + (s.y < half ? 0 : N);
                int pos = row[slot] + atomicAdd(&fill[slot], 1);
                csr[pos] = (unsigned short)s.y;
            }
            if (d.z >= lo && d.z < hi) {
                int slot = d.z + (s.z < half ? 0 : N);
                int pos = row[slot] + atomicAdd(&fill[slot], 1);
                csr[pos] = (unsigned short)s.z;
            }
            if (d.w >= lo && d.w < hi) {
                int slot = d.w + (s.w < half ? 0 : N);
                int pos = row[slot] + atomicAdd(&fill[slot], 1);
                csr[pos] = (unsigned short)s.w;
            }
        } else {
            for (; e < E; e++) {
                int d = dst[e];
                if (d >= lo && d < hi) {
                    int s = src[e];
                    int slot = d + (s < half ? 0 : N);
                    int pos = row[slot] + atomicAdd(&fill[slot], 1);
                    csr[pos] = (unsigned short)s;
                }
            }
        }
    }
}

// ---- GEMM: C = (A @ W) * dinv[row], C channel-blocked [4][ns][32] ---------
__global__ __launch_bounds__(256) void gemm_kernel(const float* __restrict__ A,
                                                   const float* __restrict__ W,
                                                   const float* __restrict__ dinv,
                                                   float* __restrict__ C, int n, int ns,
                                                   int a_blocked) {
    __shared__ float sW[128 * 32];
    int t = threadIdx.x;
    int col0 = (blockIdx.x & 3) * 32;
    int row0 = (blockIdx.x >> 2) * 64;

    #pragma unroll
    for (int i = 0; i < 4; i++) {
        int fidx = t + 256 * i;            // 1024 float4
        int k  = fidx >> 3;
        int c4 = fidx & 7;
        *(float4*)(sW + k * 32 + c4 * 4) =
            *(const float4*)(W + (size_t)k * 128 + col0 + c4 * 4);
    }
    __syncthreads();

    int cg = (t & 7) * 4;
    int rg = (t >> 3) * 2;
    int rbase = row0 + rg;

    int rr_[2];
    #pragma unroll
    for (int r = 0; r < 2; r++) {
        int rr = rbase + r; if (rr > n - 1) rr = n - 1;
        rr_[r] = rr;
    }
    auto aptr = [&](int r, int kb) -> const float* {
        return a_blocked
            ? (A + ((size_t)(kb >> 1) * ns + rr_[r]) * 32 + ((kb & 1) * 16))
            : (A + (size_t)rr_[r] * 128 + kb * 16);
    };

    float acc[2][4];
    #pragma unroll
    for (int r = 0; r < 2; r++)
        #pragma unroll
        for (int c = 0; c < 4; c++) acc[r][c] = 0.f;

    float4 bufA[2][2], bufB[2][2];
    #pragma unroll
    for (int r = 0; r < 2; r++) {
        const float* ap = aptr(r, 0);
        bufA[r][0] = *(const float4*)(ap + 0);
        bufA[r][1] = *(const float4*)(ap + 4);
        bufB[r][0] = *(const float4*)(ap + 8);
        bufB[r][1] = *(const float4*)(ap + 12);
    }

    #pragma unroll 1
    for (int kb = 0; kb < 8; kb++) {
        const float* wrow = sW + kb * 16 * 32 + cg;
        #pragma unroll
        for (int kk = 0; kk < 8; kk++) {
            float4 w = *(const float4*)(wrow + kk * 32);
            #pragma unroll
            for (int r = 0; r < 2; r++) {
                float4 aq = bufA[r][kk >> 2];
                float av = ((kk & 3) == 0) ? aq.x : ((kk & 3) == 1) ? aq.y
                         : ((kk & 3) == 2) ? aq.z : aq.w;
                acc[r][0] = fmaf(av, w.x, acc[r][0]);
                acc[r][1] = fmaf(av, w.y, acc[r][1]);
                acc[r][2] = fmaf(av, w.z, acc[r][2]);
                acc[r][3] = fmaf(av, w.w, acc[r][3]);
            }
        }
        if (kb < 7) {
            #pragma unroll
            for (int r = 0; r < 2; r++) {
                const float* ap = aptr(r, kb + 1);
                bufA[r][0] = *(const float4*)(ap + 0);
                bufA[r][1] = *(const float4*)(ap + 4);
            }
        }
        #pragma unroll
        for (int kk = 0; kk < 8; kk++) {
            float4 w = *(const float4*)(wrow + (8 + kk) * 32);
            #pragma unroll
            for (int r = 0; r < 2; r++) {
                float4 aq = bufB[r][kk >> 2];
                float av = ((kk & 3) == 0) ? aq.x : ((kk & 3) == 1) ? aq.y
                         : ((kk & 3) == 2) ? aq.z : aq.w;
                acc[r][0] = fmaf(av, w.x, acc[r][0]);
                acc[r][1] = fmaf(av, w.y, acc[r][1]);
                acc[r][2] = fmaf(av, w.z, acc[r][2]);
                acc[r][3] = fmaf(av, w.w, acc[r][3]);
            }
        }
        if (kb < 7) {
            #pragma unroll
            for (int r = 0; r < 2; r++) {
                const float* ap = aptr(r, kb + 1);
                bufB[r][0] = *(const float4*)(ap + 8);
                bufB[r][1] = *(const float4*)(ap + 12);
            }
        }
    }

    int cb = col0 + cg;
    float* Cb = C + (size_t)(cb >> 5) * ns * 32 + (cb & 31);
    #pragma unroll
    for (int r = 0; r < 2; r++) {
        int rr = rbase + r;
        if (rr < n) {
            float dsc = dinv[rr];
            *(float4*)(Cb + (size_t)rr * 32) =
                make_float4(acc[r][0] * dsc, acc[r][1] * dsc,
                            acc[r][2] * dsc, acc[r][3] * dsc);
        }
    }
}

// ---- Agg pass 1: lo-half gathers only; store raw partial sums -------------
__global__ __launch_bounds__(256) void agg_pass1_kernel(const float* __restrict__ h,
                                                        const int* __restrict__ row_ptr,
                                                        const unsigned short* __restrict__ csr,
                                                        float* __restrict__ out,
                                                        int n, int ns) {
    int p = blockIdx.x & 3;
    int i = (blockIdx.x >> 2) * 32 + (threadIdx.x >> 3);
    int q = threadIdx.x & 7;
    bool valid = (i < n);
    int iv = valid ? i : 0;

    const float* slice  = h   + (size_t)p * ns * 32;
    float*       oslice = out + (size_t)p * ns * 32;

    int beg = row_ptr[iv];
    int end = valid ? row_ptr[iv + 1] : beg;
    int qoff = q << 2;

    float4 acc = make_float4(0.f, 0.f, 0.f, 0.f);

    int e = beg;
    int s0 = (int)__builtin_nontemporal_load(csr + e);
    int s1 = (int)__builtin_nontemporal_load(csr + e + 1);
    int s2 = (int)__builtin_nontemporal_load(csr + e + 2);
    int s3 = (int)__builtin_nontemporal_load(csr + e + 3);

    while (__any(e < end)) {
        int en = e + 4;
        int t0 = (int)__builtin_nontemporal_load(csr + en);
        int t1 = (int)__builtin_nontemporal_load(csr + en + 1);
        int t2 = (int)__builtin_nontemporal_load(csr + en + 2);
        int t3 = (int)__builtin_nontemporal_load(csr + en + 3);

        int g0 = (e     < end) ? s0 : n;
        int g1 = (e + 1 < end) ? s1 : n;
        int g2 = (e + 2 < end) ? s2 : n;
        int g3 = (e + 3 < end) ? s3 : n;

        float4 v0 = *(const float4*)(slice + ((size_t)g0 << 5) + qoff);
        float4 v1 = *(const float4*)(slice + ((size_t)g1 << 5) + qoff);
        float4 v2 = *(const float4*)(slice + ((size_t)g2 << 5) + qoff);
        float4 v3 = *(const float4*)(slice + ((size_t)g3 << 5) + qoff);

        acc.x += v0.x; acc.y += v0.y; acc.z += v0.z; acc.w += v0.w;
        acc.x += v1.x; acc.y += v1.y; acc.z += v1.z; acc.w += v1.w;
        acc.x += v2.x; acc.y += v2.y; acc.z += v2.z; acc.w += v2.w;
        acc.x += v3.x; acc.y += v3.y; acc.z += v3.z; acc.w += v3.w;

        e = en; s0 = t0; s1 = t1; s2 = t2; s3 = t3;
    }

    if (valid)
        *(float4*)(oslice + ((size_t)i << 5) + qoff) = acc;
}

// ---- Agg pass 2: hi-half gathers + partial + self + epilogue --------------
// out[i] = relu( (hi_sum + partial + slice[i]) * dinv[i] + b )
__global__ __launch_bounds__(256) void agg_pass2_kernel(const float* __restrict__ h,
                                                        const int* __restrict__ row_ptr,
                                                        const unsigned short* __restrict__ csr,
                                                        const float* __restrict__ dinv,
                                                        const float* __restrict__ bias,
                                                        float* __restrict__ out,
                                                        int n, int ns) {
    int p = blockIdx.x & 3;
    int i = (blockIdx.x >> 2) * 32 + (threadIdx.x >> 3);
    int q = threadIdx.x & 7;
    bool valid = (i < n);
    int iv = valid ? i : 0;

    const float* slice  = h   + (size_t)p * ns * 32;
    float*       oslice = out + (size_t)p * ns * 32;

    int beg = row_ptr[iv];
    int end = valid ? row_ptr[iv + 1] : beg;
    int qoff = q << 2;

    float4 acc = make_float4(0.f, 0.f, 0.f, 0.f);

    int e = beg;
    int s0 = (int)__builtin_nontemporal_load(csr + e);
    int s1 = (int)__builtin_nontemporal_load(csr + e + 1);
    int s2 = (int)__builtin_nontemporal_load(csr + e + 2);
    int s3 = (int)__builtin_nontemporal_load(csr + e + 3);

    while (__any(e < end)) {
        int en = e + 4;
        int t0 = (int)__builtin_nontemporal_load(csr + en);
        int t1 = (int)__builtin_nontemporal_load(csr + en + 1);
        int t2 = (int)__builtin_nontemporal_load(csr + en + 2);
        int t3 = (int)__builtin_nontemporal_load(csr + en + 3);

        int g0 = (e     < end) ? s0 : n;
        int g1 = (e + 1 < end) ? s1 : n;
        int g2 = (e + 2 < end) ? s2 : n;
        int g3 = (e + 3 < end) ? s3 : n;

        float4 v0 = *(const float4*)(slice + ((size_t)g0 << 5) + qoff);
        float4 v1 = *(const float4*)(slice + ((size_t)g1 << 5) + qoff);
        float4 v2 = *(const float4*)(slice + ((size_t)g2 << 5) + qoff);
        float4 v3 = *(const float4*)(slice + ((size_t)g3 << 5) + qoff);

        acc.x += v0.x; acc.y += v0.y; acc.z += v0.z; acc.w += v0.w;
        acc.x += v1.x; acc.y += v1.y; acc.z += v1.z; acc.w += v1.w;
        acc.x += v2.x; acc.y += v2.y; acc.z += v2.z; acc.w += v2.w;
        acc.x += v3.x; acc.y += v3.y; acc.z += v3.z; acc.w += v3.w;

        e = en; s0 = t0; s1 = t1; s2 = t2; s3 = t3;
    }

    if (valid) {
        float di = dinv[i];
        float4 part = *(float4*)(oslice + ((size_t)i << 5) + qoff);
        float4 self = *(const float4*)(slice + ((size_t)i << 5) + qoff);
        float4 b4   = *(const float4*)(bias + p * 32 + qoff);
        float4 o;
        o.x = fmaxf(fmaf(acc.x + part.x + self.x, di, b4.x), 0.f);
        o.y = fmaxf(fmaf(acc.y + part.y + self.y, di, b4.y), 0.f);
        o.z = fmaxf(fmaf(acc.z + part.z + self.z, di, b4.z), 0.f);
        o.w = fmaxf(fmaf(acc.w + part.w + self.w, di, b4.w), 0.f);
        *(float4*)(oslice + ((size_t)i << 5) + qoff) = o;
    }
}

// ---- pool stage 1: deterministic fp64 partials, one slot per (g,s) --------
__global__ __launch_bounds__(128) void pool_partial_kernel(const float* __restrict__ h,
                                                           const int* __restrict__ batch,
                                                           double* __restrict__ partials,
                                                           int n, int ns, int S) {
    int g = blockIdx.x / S;
    int s = blockIdx.x % S;
    int c = threadIdx.x;
    const float* hb = h + (size_t)(c >> 5) * ns * 32 + (c & 31);

    int lo = 0, hi = n;
    while (lo < hi) { int mid = (lo + hi) >> 1; if (batch[mid] < g) lo = mid + 1; else hi = mid; }
    int start = lo;
    lo = start; hi = n;
    while (lo < hi) { int mid = (lo + hi) >> 1; if (batch[mid] < g + 1) lo = mid + 1; else hi = mid; }
    int end = lo;

    int cnt = end - start;
    int per = (cnt + S - 1) / S;
    int rs = start + s * per;
    int re = rs + per; if (re > end) re = end;

    double a0 = 0.0, a1 = 0.0, a2 = 0.0, a3 = 0.0;
    int r = rs;
    for (; r + 4 <= re; r += 4) {
        a0 += (double)hb[(size_t)(r + 0) * 32];
        a1 += (double)hb[(size_t)(r + 1) * 32];
        a2 += (double)hb[(size_t)(r + 2) * 32];
        a3 += (double)hb[(size_t)(r + 3) * 32];
    }
    for (; r < re; r++) a0 += (double)hb[(size_t)r * 32];
    partials[(size_t)(g * S + s) * 128 + c] = (a0 + a1) + (a2 + a3);
}

// ---- pool stage 2: reduce S partials, mean + FC(128->1), fp64 -------------
__global__ __launch_bounds__(128) void pool_fc_final_kernel(const double* __restrict__ partials,
                                                            const int* __restrict__ batch,
                                                            const float* __restrict__ Wfc,
                                                            const float* __restrict__ bfc,
                                                            float* __restrict__ out,
                                                            int n, int S) {
    int g = blockIdx.x;
    int c = threadIdx.x;

    int lo = 0, hi = n;
    while (lo < hi) { int mid = (lo + hi) >> 1; if (batch[mid] < g) lo = mid + 1; else hi = mid; }
    int start = lo;
    lo = start; hi = n;
    while (lo < hi) { int mid = (lo + hi) >> 1; if (batch[mid] < g + 1) lo = mid + 1; else hi = mid; }
    int cnt = lo - start;

    double sum = 0.0;
    for (int s = 0; s < S; s++) sum += partials[(size_t)(g * S + s) * 128 + c];
    double mean = sum / (double)(cnt > 0 ? cnt : 1);
    double v = mean * (double)Wfc[c];

    __shared__ double red[128];
    red[c] = v;
    __syncthreads();
    for (int off = 64; off > 0; off >>= 1) {
        if (c < off) red[c] += red[c + off];
        __syncthreads();
    }
    if (c == 0) out[g] = (float)(red[0] + (double)bfc[0]);
}

// ---------------------------------------------------------------------------
extern "C" void kernel_launch(void* const* d_in, const int* in_sizes, int n_in,
                              void* d_out, int out_size, void* d_ws, size_t ws_size,
                              hipStream_t stream) {
    const float* x          = (const float*)d_in[0];
    const int*   edge_index = (const int*)d_in[1];
    const int*   batch      = (const int*)d_in[2];
    const float* W1  = (const float*)d_in[3];
    const float* b1  = (const float*)d_in[4];
    const float* W2  = (const float*)d_in[5];
    const float* b2  = (const float*)d_in[6];
    const float* Wfc = (const float*)d_in[7];
    const float* bfc = (const float*)d_in[8];
    float* out = (float*)d_out;

    const int N = in_sizes[2];       // 50000
    const int E = in_sizes[1] / 2;   // 1600000
    const int G = out_size;          // 128 graphs
    const int NS = N + 1;            // slice stride in rows (pad row = zeros)
    const int HALF = N >> 1;
    const int N2 = 2 * N;

    const int* e_src = edge_index;
    const int* e_dst = edge_index + E;

    char* p = (char*)d_ws;
    auto alloc = [&](size_t bytes) {
        void* r = (void*)p;
        p += (bytes + 255) & ~(size_t)255;
        return r;
    };
    const int S = 8;
    const int NB = (N2 + 255) / 256;    // scan blocks (391)
    float*          h0        = (float*)alloc((size_t)NS * 128 * 4);
    float*          h1        = (float*)alloc((size_t)NS * 128 * 4);
    unsigned short* csr       = (unsigned short*)alloc(((size_t)E + 1024) * 2);
    int*            row       = (int*)  alloc((size_t)(N2 + 1) * 4);
    int*            deg       = (int*)  alloc((size_t)N2 * 4);
    int*            fill      = (int*)  alloc((size_t)N2 * 4);
    int*            bsum      = (int*)  alloc((size_t)NB * 4);
    int*            boff      = (int*)  alloc((size_t)NB * 4);
    float*          dinv      = (float*)alloc((size_t)N * 4);
    double*         partials  = (double*)alloc((size_t)G * S * 128 * 8);
    (void)ws_size; (void)n_in;

    hipMemsetAsync(deg,  0, (size_t)N2 * 4, stream);
    hipMemsetAsync(fill, 0, (size_t)N2 * 4, stream);

    int tb = 256;
    int e4 = (E + 3) / 4;
    count_deg_kernel<<<(e4 + tb - 1) / tb, tb, 0, stream>>>(e_src, e_dst, deg, E, HALF, N);
    dinv_kernel<<<(N + tb - 1) / tb, tb, 0, stream>>>(deg, dinv, h0, h1, N, NS);
    scan_blocksum_kernel<<<NB, 256, 0, stream>>>(deg, bsum, N2);
    scan_bsum_kernel<<<1, 1024, 0, stream>>>(bsum, boff, NB);
    scan_final_kernel<<<NB, 256, 0, stream>>>(deg, boff, row, N2);
    csr_fill_kernel<<<1024, tb, 0, stream>>>(e_src, e_dst, row, fill, csr, E, N, HALF);

    int gemm_blocks = 4 * ((N + 63) / 64);
    int agg_blocks  = 4 * ((N + 31) / 32);

    gemm_kernel<<<gemm_blocks, 256, 0, stream>>>(x, W1, dinv, h1, N, NS, 0);
    agg_pass1_kernel<<<agg_blocks, 256, 0, stream>>>(h1, row,     csr, h0, N, NS);
    agg_pass2_kernel<<<agg_blocks, 256, 0, stream>>>(h1, row + N, csr, dinv, b1, h0, N, NS);

    for (int l = 0; l < 3; l++) {
        gemm_kernel<<<gemm_blocks, 256, 0, stream>>>(h0, W2, dinv, h1, N, NS, 1);
        agg_pass1_kernel<<<agg_blocks, 256, 0, stream>>>(h1, row,     csr, h0, N, NS);
        agg_pass2_kernel<<<agg_blocks, 256, 0, stream>>>(h1, row + N, csr, dinv, b2, h0, N, NS);
    }

    pool_partial_kernel<<<G * S, 128, 0, stream>>>(h0, batch, partials, N, NS, S);
    pool_fc_final_kernel<<<G, 128, 0, stream>>>(partials, batch, Wfc, bfc, out, N, S);
}